// Round 2
// baseline (1048.771 us; speedup 1.0000x reference)
//
#include <hip/hip_runtime.h>

#define N_NODES 10000
#define N_EDGES 160000

// ---------------- CSR build ----------------
__global__ void count_kernel(const int* __restrict__ ei, int* __restrict__ deg) {
    int e = blockIdx.x * blockDim.x + threadIdx.x;
    if (e < N_EDGES) {
        int dst = ei[N_EDGES + e];
        atomicAdd(&deg[dst], 1);
    }
}

__global__ void scanA_kernel(const int* __restrict__ deg, int* __restrict__ row_start,
                             int* __restrict__ chunk_tot) {
    __shared__ int s[256];
    int c = blockIdx.x, tid = threadIdx.x;
    int i = c * 256 + tid;
    int v = (i < N_NODES) ? deg[i] : 0;
    s[tid] = v;
    __syncthreads();
    for (int off = 1; off < 256; off <<= 1) {
        int t = (tid >= off) ? s[tid - off] : 0;
        __syncthreads();
        s[tid] += t;
        __syncthreads();
    }
    if (i < N_NODES) row_start[i + 1] = s[tid];
    if (tid == 255) chunk_tot[c] = s[255];
}

__global__ void scanC_kernel(int* __restrict__ row_start, const int* __restrict__ chunk_tot) {
    int c = blockIdx.x, tid = threadIdx.x;
    int off = 0;
    for (int cc = 0; cc < c; ++cc) off += chunk_tot[cc];
    int i = c * 256 + tid;
    if (i < N_NODES) row_start[i + 1] += off;
    if (c == 0 && tid == 0) row_start[0] = 0;
}

__global__ void scatter_kernel(const int* __restrict__ ei, const int* __restrict__ row_start,
                               int* __restrict__ cursor, int* __restrict__ csr_src) {
    int e = blockIdx.x * blockDim.x + threadIdx.x;
    if (e < N_EDGES) {
        int src = ei[e];
        int dst = ei[N_EDGES + e];
        int p = atomicAdd(&cursor[dst], 1);
        csr_src[row_start[dst] + p] = src;
    }
}

// ---------------- z = x @ [W_l | W_r]  ([10000,512] @ [512,512] -> [10000,512]) ----------------
// 128x128 tile, 8x8 microtile per thread, BK=16, register-prefetch double buffer.
// Z cols 0..255 = x@W_l, cols 256..511 = x@W_r.
__global__ __launch_bounds__(256, 2) void zgemm_kernel(const float* __restrict__ x,
                                                       const float* __restrict__ W_l,
                                                       const float* __restrict__ W_r,
                                                       float* __restrict__ Z) {
    __shared__ float As[16][132];  // [k][m] transposed; pad keeps float4 align, ~2-way max
    __shared__ float Bs[16][132];  // [k][n]
    int tid = threadIdx.x;
    int rowbase = blockIdx.y * 128;
    int bx = blockIdx.x;                       // 0..3
    const float* B = (bx < 2) ? W_l : W_r;
    int colb = (bx & 1) * 128;                 // col offset within the 256-wide weight

    // staging map: A tile 128x16 -> 512 float4, 2 per thread
    int ar  = tid >> 2;            // 0..63 (and +64)
    int ac4 = (tid & 3) << 2;      // 0,4,8,12
    // B tile 16x128 -> 512 float4, 2 per thread
    int bkr = tid >> 5;            // 0..7 (and +8)
    int bc4 = (tid & 31) << 2;     // 0..124

    int r0 = min(rowbase + ar, N_NODES - 1);
    int r1 = min(rowbase + ar + 64, N_NODES - 1);
    const float* a0p = x + (size_t)r0 * 512 + ac4;
    const float* a1p = x + (size_t)r1 * 512 + ac4;
    const float* b0p = B + (size_t)bkr * 256 + colb + bc4;
    const float* b1p = B + (size_t)(bkr + 8) * 256 + colb + bc4;

    float4 pa0 = *(const float4*)(a0p);
    float4 pa1 = *(const float4*)(a1p);
    float4 pb0 = *(const float4*)(b0p);
    float4 pb1 = *(const float4*)(b1p);

    // initial LDS fill
    As[ac4 + 0][ar] = pa0.x; As[ac4 + 1][ar] = pa0.y; As[ac4 + 2][ar] = pa0.z; As[ac4 + 3][ar] = pa0.w;
    As[ac4 + 0][ar + 64] = pa1.x; As[ac4 + 1][ar + 64] = pa1.y; As[ac4 + 2][ar + 64] = pa1.z; As[ac4 + 3][ar + 64] = pa1.w;
    *(float4*)&Bs[bkr][bc4] = pb0;
    *(float4*)&Bs[bkr + 8][bc4] = pb1;
    __syncthreads();

    float acc[8][8] = {};
    int tm = (tid & 15) << 3;
    int tn = (tid >> 4) << 3;

    for (int kt = 0; kt < 512; kt += 16) {
        bool more = (kt + 16) < 512;
        if (more) {
            pa0 = *(const float4*)(a0p + kt + 16);
            pa1 = *(const float4*)(a1p + kt + 16);
            pb0 = *(const float4*)(b0p + (size_t)(kt + 16) * 256);
            pb1 = *(const float4*)(b1p + (size_t)(kt + 16) * 256);
        }
#pragma unroll
        for (int kk = 0; kk < 16; ++kk) {
            float4 av0 = *(const float4*)&As[kk][tm];
            float4 av1 = *(const float4*)&As[kk][tm + 4];
            float4 bv0 = *(const float4*)&Bs[kk][tn];
            float4 bv1 = *(const float4*)&Bs[kk][tn + 4];
            float a[8] = {av0.x, av0.y, av0.z, av0.w, av1.x, av1.y, av1.z, av1.w};
            float b[8] = {bv0.x, bv0.y, bv0.z, bv0.w, bv1.x, bv1.y, bv1.z, bv1.w};
#pragma unroll
            for (int i = 0; i < 8; ++i)
#pragma unroll
                for (int j = 0; j < 8; ++j) acc[i][j] += a[i] * b[j];
        }
        __syncthreads();
        if (more) {
            As[ac4 + 0][ar] = pa0.x; As[ac4 + 1][ar] = pa0.y; As[ac4 + 2][ar] = pa0.z; As[ac4 + 3][ar] = pa0.w;
            As[ac4 + 0][ar + 64] = pa1.x; As[ac4 + 1][ar + 64] = pa1.y; As[ac4 + 2][ar + 64] = pa1.z; As[ac4 + 3][ar + 64] = pa1.w;
            *(float4*)&Bs[bkr][bc4] = pb0;
            *(float4*)&Bs[bkr + 8][bc4] = pb1;
        }
        __syncthreads();
    }

#pragma unroll
    for (int i = 0; i < 8; ++i) {
        int row = rowbase + tm + i;
        if (row >= N_NODES) continue;
        float* zr = Z + (size_t)row * 512 + bx * 128 + tn;
        *(float4*)(zr)     = make_float4(acc[i][0], acc[i][1], acc[i][2], acc[i][3]);
        *(float4*)(zr + 4) = make_float4(acc[i][4], acc[i][5], acc[i][6], acc[i][7]);
    }
}

// ---------------- fused mean-aggregation + SAGE epilogue ----------------
// h1[dst] = relu( mean_{src->dst} z[src, 0:256] + z[dst, 256:512] + b_l )
// one wave per dst; lane owns 4 consecutive floats (64*4 = 256)
__global__ __launch_bounds__(256) void aggr_fused_kernel(const float* __restrict__ z,
                                                         const int* __restrict__ csr_src,
                                                         const int* __restrict__ row_start,
                                                         const float* __restrict__ b_l,
                                                         float* __restrict__ h1) {
    int lane = threadIdx.x & 63;
    int dst = blockIdx.x * 4 + (threadIdx.x >> 6);
    int beg = row_start[dst], end = row_start[dst + 1];
    float4 acc = make_float4(0.f, 0.f, 0.f, 0.f);
    int i = beg;
    for (; i + 1 < end; i += 2) {
        int s0 = csr_src[i];
        int s1 = csr_src[i + 1];
        float4 v0 = *((const float4*)(z + (size_t)s0 * 512) + lane);
        float4 v1 = *((const float4*)(z + (size_t)s1 * 512) + lane);
        acc.x += v0.x + v1.x; acc.y += v0.y + v1.y;
        acc.z += v0.z + v1.z; acc.w += v0.w + v1.w;
    }
    if (i < end) {
        int s0 = csr_src[i];
        float4 v0 = *((const float4*)(z + (size_t)s0 * 512) + lane);
        acc.x += v0.x; acc.y += v0.y; acc.z += v0.z; acc.w += v0.w;
    }
    float inv = 1.0f / (float)max(end - beg, 1);
    float4 r = *((const float4*)(z + (size_t)dst * 512 + 256) + lane);
    float4 bb = *((const float4*)b_l + lane);
    float4 o;
    o.x = fmaxf(fmaf(acc.x, inv, r.x + bb.x), 0.f);
    o.y = fmaxf(fmaf(acc.y, inv, r.y + bb.y), 0.f);
    o.z = fmaxf(fmaf(acc.z, inv, r.z + bb.z), 0.f);
    o.w = fmaxf(fmaf(acc.w, inv, r.w + bb.w), 0.f);
    *((float4*)(h1 + (size_t)dst * 256) + lane) = o;
}

// ---------------- generic fp32 tiled GEMM: C = act(A@B + bias) ----------------
template <bool RELU>
__global__ __launch_bounds__(256) void gemm_kernel(const float* __restrict__ A,
                                                   const float* __restrict__ B,
                                                   const float* __restrict__ bias,
                                                   float* __restrict__ C,
                                                   int M, int K, int N) {
    const int BK = 32;
    __shared__ float As[32][68];
    __shared__ float Bs[32][68];
    int tid = threadIdx.x;
    int rowbase = blockIdx.y * 64;
    int colbase = blockIdx.x * 64;
    float acc[4][4] = {};

    for (int kt = 0; kt < K; kt += BK) {
        {
            int r = tid >> 3;
            int c4 = (tid & 7) * 4;
#pragma unroll
            for (int h = 0; h < 2; ++h) {
                int row = rowbase + r + h * 32;
                int arow = min(row, M - 1);
                float4 v = *(const float4*)(A + (size_t)arow * K + kt + c4);
                As[c4 + 0][r + h * 32] = v.x;
                As[c4 + 1][r + h * 32] = v.y;
                As[c4 + 2][r + h * 32] = v.z;
                As[c4 + 3][r + h * 32] = v.w;
            }
        }
        {
            int kr = tid >> 4;
            int c4 = (tid & 15) * 4;
#pragma unroll
            for (int h = 0; h < 2; ++h) {
                int k = kt + kr + h * 16;
                int col = colbase + c4;
                float4 v;
                if (col + 4 <= N) {
                    v = *(const float4*)(B + (size_t)k * N + col);
                } else {
                    v.x = (col + 0 < N) ? B[(size_t)k * N + col + 0] : 0.f;
                    v.y = (col + 1 < N) ? B[(size_t)k * N + col + 1] : 0.f;
                    v.z = (col + 2 < N) ? B[(size_t)k * N + col + 2] : 0.f;
                    v.w = (col + 3 < N) ? B[(size_t)k * N + col + 3] : 0.f;
                }
                *(float4*)&Bs[kr + h * 16][c4] = v;
            }
        }
        __syncthreads();
        int tm = (tid & 15) * 4;
        int tn = (tid >> 4) * 4;
#pragma unroll
        for (int kk = 0; kk < BK; ++kk) {
            float4 av = *(const float4*)&As[kk][tm];
            float4 bv = *(const float4*)&Bs[kk][tn];
            float a[4] = {av.x, av.y, av.z, av.w};
            float b[4] = {bv.x, bv.y, bv.z, bv.w};
#pragma unroll
            for (int i = 0; i < 4; ++i)
#pragma unroll
                for (int j = 0; j < 4; ++j) acc[i][j] += a[i] * b[j];
        }
        __syncthreads();
    }

    int tm = (tid & 15) * 4;
    int tn = (tid >> 4) * 4;
#pragma unroll
    for (int i = 0; i < 4; ++i) {
        int row = rowbase + tm + i;
        if (row >= M) continue;
#pragma unroll
        for (int j = 0; j < 4; ++j) {
            int col = colbase + tn + j;
            if (col >= N) continue;
            float v = acc[i][j] + bias[col];
            if (RELU) v = fmaxf(v, 0.f);
            C[(size_t)row * N + col] = v;
        }
    }
}

// ---------------- pairwise L2 on [N,3] ----------------
__global__ __launch_bounds__(256) void dist_kernel(const float* __restrict__ y,
                                                   float* __restrict__ out) {
    __shared__ float sa[192];
    __shared__ float sb[192];
    int rb = blockIdx.y * 64;
    int cb = blockIdx.x * 64;
    int tid = threadIdx.x;
    if (tid < 192) {
        int ga = rb * 3 + tid;
        sa[tid] = (ga < 3 * N_NODES) ? y[ga] : 0.f;
        int gb = cb * 3 + tid;
        sb[tid] = (gb < 3 * N_NODES) ? y[gb] : 0.f;
    }
    __syncthreads();
    int ty = tid >> 4;
    int tx = tid & 15;
    int c0 = tx * 4;
#pragma unroll
    for (int i = 0; i < 4; ++i) {
        int r = ty * 4 + i;
        int row = rb + r;
        if (row >= N_NODES) continue;
        float ax = sa[r * 3 + 0], ay = sa[r * 3 + 1], az = sa[r * 3 + 2];
        float res[4];
#pragma unroll
        for (int j = 0; j < 4; ++j) {
            int cc = c0 + j;
            float dx = ax - sb[cc * 3 + 0];
            float dy = ay - sb[cc * 3 + 1];
            float dz = az - sb[cc * 3 + 2];
            res[j] = sqrtf(dx * dx + dy * dy + dz * dz);
        }
        int col = cb + c0;
        size_t base = (size_t)row * N_NODES + col;
        if (col + 4 <= N_NODES) {
            *(float4*)(out + base) = make_float4(res[0], res[1], res[2], res[3]);
        } else {
#pragma unroll
            for (int j = 0; j < 4; ++j)
                if (col + j < N_NODES) out[base + j] = res[j];
        }
    }
}

extern "C" void kernel_launch(void* const* d_in, const int* in_sizes, int n_in,
                              void* d_out, int out_size, void* d_ws, size_t ws_size,
                              hipStream_t stream) {
    const float* x   = (const float*)d_in[0];
    const int*   ei  = (const int*)d_in[1];
    const float* W_l = (const float*)d_in[2];
    const float* b_l = (const float*)d_in[3];
    const float* W_r = (const float*)d_in[4];
    const float* Wa  = (const float*)d_in[5];
    const float* ba  = (const float*)d_in[6];
    const float* W1  = (const float*)d_in[7];
    const float* b1  = (const float*)d_in[8];
    const float* W2  = (const float*)d_in[9];
    const float* b2  = (const float*)d_in[10];
    const float* W3  = (const float*)d_in[11];
    const float* b3  = (const float*)d_in[12];

    float* out = (float*)d_out;
    // big intermediates live in d_out (fully overwritten by dist_kernel at the end)
    float* z    = out;                 // 10000*512 = 5,120,000 f   (x@[W_l|W_r])
    float* h1   = out + 5120000;       // 10000*256 = 2,560,000 f
    float* h2   = out + 7680000;       // 10000*128 = 1,280,000 f
    float* h3   = out + 8960000;       // 10000*64  =   640,000 f
    float* h4   = out + 9600000;       // 10000*32  =   320,000 f

    // small stuff in d_ws (~880 KB)
    float* y        = (float*)d_ws;            // 30,000 f
    int* deg        = (int*)d_ws + 30000;      // 10,000
    int* row_start  = (int*)d_ws + 40000;      // 10,001
    int* cursor     = (int*)d_ws + 50016;      // 10,000
    int* chunk_tot  = (int*)d_ws + 60016;      // 40
    int* csr_src    = (int*)d_ws + 60064;      // 160,000

    hipMemsetAsync(deg, 0, N_NODES * sizeof(int), stream);
    hipMemsetAsync(cursor, 0, N_NODES * sizeof(int), stream);

    // z = x @ [W_l | W_r] : independent of CSR; issue first
    zgemm_kernel<<<dim3(4, 79), 256, 0, stream>>>(x, W_l, W_r, z);

    count_kernel<<<(N_EDGES + 255) / 256, 256, 0, stream>>>(ei, deg);
    scanA_kernel<<<40, 256, 0, stream>>>(deg, row_start, chunk_tot);
    scanC_kernel<<<40, 256, 0, stream>>>(row_start, chunk_tot);
    scatter_kernel<<<(N_EDGES + 255) / 256, 256, 0, stream>>>(ei, row_start, cursor, csr_src);

    // h1 = relu(mean(z_l[src]) + z_r[dst] + b_l)
    aggr_fused_kernel<<<2500, 256, 0, stream>>>(z, csr_src, row_start, b_l, h1);

    dim3 b256(256);
    // h2 = relu(h1@Wa + ba)               [10000,128]
    gemm_kernel<true><<<dim3(2, 157), b256, 0, stream>>>(h1, Wa, ba, h2, N_NODES, 256, 128);
    // h3 = relu(h2@W1 + b1)               [10000,64]
    gemm_kernel<true><<<dim3(1, 157), b256, 0, stream>>>(h2, W1, b1, h3, N_NODES, 128, 64);
    // h4 = relu(h3@W2 + b2)               [10000,32]
    gemm_kernel<true><<<dim3(1, 157), b256, 0, stream>>>(h3, W2, b2, h4, N_NODES, 64, 32);
    // y  = h4@W3 + b3                     [10000,3]
    gemm_kernel<false><<<dim3(1, 157), b256, 0, stream>>>(h4, W3, b3, y, N_NODES, 32, 3);

    dist_kernel<<<dim3(157, 157), b256, 0, stream>>>(y, out);
}

// Round 3
// 647.938 us; speedup vs baseline: 1.6186x; 1.6186x over previous
//
#include <hip/hip_runtime.h>

#define N_NODES 10000
#define N_EDGES 160000

// ---------------- CSR build ----------------
__global__ void count_kernel(const int* __restrict__ ei, int* __restrict__ deg) {
    int e = blockIdx.x * blockDim.x + threadIdx.x;
    if (e < N_EDGES) {
        int dst = ei[N_EDGES + e];
        atomicAdd(&deg[dst], 1);
    }
}

__global__ void scanA_kernel(const int* __restrict__ deg, int* __restrict__ row_start,
                             int* __restrict__ chunk_tot) {
    __shared__ int s[256];
    int c = blockIdx.x, tid = threadIdx.x;
    int i = c * 256 + tid;
    int v = (i < N_NODES) ? deg[i] : 0;
    s[tid] = v;
    __syncthreads();
    for (int off = 1; off < 256; off <<= 1) {
        int t = (tid >= off) ? s[tid - off] : 0;
        __syncthreads();
        s[tid] += t;
        __syncthreads();
    }
    if (i < N_NODES) row_start[i + 1] = s[tid];
    if (tid == 255) chunk_tot[c] = s[255];
}

__global__ void scanC_kernel(int* __restrict__ row_start, const int* __restrict__ chunk_tot) {
    int c = blockIdx.x, tid = threadIdx.x;
    int off = 0;
    for (int cc = 0; cc < c; ++cc) off += chunk_tot[cc];
    int i = c * 256 + tid;
    if (i < N_NODES) row_start[i + 1] += off;
    if (c == 0 && tid == 0) row_start[0] = 0;
}

__global__ void scatter_kernel(const int* __restrict__ ei, const int* __restrict__ row_start,
                               int* __restrict__ cursor, int* __restrict__ csr_src) {
    int e = blockIdx.x * blockDim.x + threadIdx.x;
    if (e < N_EDGES) {
        int src = ei[e];
        int dst = ei[N_EDGES + e];
        int p = atomicAdd(&cursor[dst], 1);
        csr_src[row_start[dst] + p] = src;
    }
}

// ---------------- z = x @ [W_l | W_r]  ([10000,512] @ [512,(256|256)] -> [10000,512]) ----------------
// Proven 64x64 tile / 4x4 microtile structure (~64 VGPR, no spill). Per-block B-pointer select.
__global__ __launch_bounds__(256) void zgemm_kernel(const float* __restrict__ x,
                                                    const float* __restrict__ W_l,
                                                    const float* __restrict__ W_r,
                                                    float* __restrict__ Z) {
    const int BK = 32;
    __shared__ float As[32][68];  // [k][m] transposed, padded
    __shared__ float Bs[32][68];  // [k][n]
    int tid = threadIdx.x;
    int rowbase = blockIdx.y * 64;
    int colbase = blockIdx.x * 64;               // 0..448
    const float* B = (colbase < 256) ? W_l : W_r;
    int bcol = colbase & 255;                    // col offset within the 256-wide weight
    float acc[4][4] = {};

    for (int kt = 0; kt < 512; kt += BK) {
        // A tile 64x32 -> LDS transposed
        {
            int r = tid >> 3;            // 0..31
            int c4 = (tid & 7) * 4;      // 0..28
#pragma unroll
            for (int h = 0; h < 2; ++h) {
                int row = rowbase + r + h * 32;
                int arow = min(row, N_NODES - 1);
                float4 v = *(const float4*)(x + (size_t)arow * 512 + kt + c4);
                As[c4 + 0][r + h * 32] = v.x;
                As[c4 + 1][r + h * 32] = v.y;
                As[c4 + 2][r + h * 32] = v.z;
                As[c4 + 3][r + h * 32] = v.w;
            }
        }
        // B tile 32x64
        {
            int kr = tid >> 4;           // 0..15
            int c4 = (tid & 15) * 4;     // 0..60
#pragma unroll
            for (int h = 0; h < 2; ++h) {
                int k = kt + kr + h * 16;
                float4 v = *(const float4*)(B + (size_t)k * 256 + bcol + c4);
                *(float4*)&Bs[kr + h * 16][c4] = v;
            }
        }
        __syncthreads();
        int tm = (tid & 15) * 4;
        int tn = (tid >> 4) * 4;
#pragma unroll
        for (int kk = 0; kk < BK; ++kk) {
            float4 av = *(const float4*)&As[kk][tm];
            float4 bv = *(const float4*)&Bs[kk][tn];
            float a[4] = {av.x, av.y, av.z, av.w};
            float b[4] = {bv.x, bv.y, bv.z, bv.w};
#pragma unroll
            for (int i = 0; i < 4; ++i)
#pragma unroll
                for (int j = 0; j < 4; ++j) acc[i][j] += a[i] * b[j];
        }
        __syncthreads();
    }

    int tm = (tid & 15) * 4;
    int tn = (tid >> 4) * 4;
#pragma unroll
    for (int i = 0; i < 4; ++i) {
        int row = rowbase + tm + i;
        if (row >= N_NODES) continue;
        float* zr = Z + (size_t)row * 512 + colbase + tn;
        *(float4*)(zr) = make_float4(acc[i][0], acc[i][1], acc[i][2], acc[i][3]);
    }
}

// ---------------- fused mean-aggregation + SAGE epilogue ----------------
// h1[dst] = relu( mean_{src->dst} z[src, 0:256] + z[dst, 256:512] + b_l )
// one wave per dst; lane owns 4 consecutive floats (64*4 = 256)
__global__ __launch_bounds__(256) void aggr_fused_kernel(const float* __restrict__ z,
                                                         const int* __restrict__ csr_src,
                                                         const int* __restrict__ row_start,
                                                         const float* __restrict__ b_l,
                                                         float* __restrict__ h1) {
    int lane = threadIdx.x & 63;
    int dst = blockIdx.x * 4 + (threadIdx.x >> 6);
    int beg = row_start[dst], end = row_start[dst + 1];
    float4 acc = make_float4(0.f, 0.f, 0.f, 0.f);
    int i = beg;
    for (; i + 1 < end; i += 2) {
        int s0 = csr_src[i];
        int s1 = csr_src[i + 1];
        float4 v0 = *((const float4*)(z + (size_t)s0 * 512) + lane);
        float4 v1 = *((const float4*)(z + (size_t)s1 * 512) + lane);
        acc.x += v0.x + v1.x; acc.y += v0.y + v1.y;
        acc.z += v0.z + v1.z; acc.w += v0.w + v1.w;
    }
    if (i < end) {
        int s0 = csr_src[i];
        float4 v0 = *((const float4*)(z + (size_t)s0 * 512) + lane);
        acc.x += v0.x; acc.y += v0.y; acc.z += v0.z; acc.w += v0.w;
    }
    float inv = 1.0f / (float)max(end - beg, 1);
    float4 r = *((const float4*)(z + (size_t)dst * 512 + 256) + lane);
    float4 bb = *((const float4*)b_l + lane);
    float4 o;
    o.x = fmaxf(fmaf(acc.x, inv, r.x + bb.x), 0.f);
    o.y = fmaxf(fmaf(acc.y, inv, r.y + bb.y), 0.f);
    o.z = fmaxf(fmaf(acc.z, inv, r.z + bb.z), 0.f);
    o.w = fmaxf(fmaf(acc.w, inv, r.w + bb.w), 0.f);
    *((float4*)(h1 + (size_t)dst * 256) + lane) = o;
}

// ---------------- generic fp32 tiled GEMM: C = act(A@B + bias) ----------------
template <bool RELU>
__global__ __launch_bounds__(256) void gemm_kernel(const float* __restrict__ A,
                                                   const float* __restrict__ B,
                                                   const float* __restrict__ bias,
                                                   float* __restrict__ C,
                                                   int M, int K, int N) {
    const int BK = 32;
    __shared__ float As[32][68];
    __shared__ float Bs[32][68];
    int tid = threadIdx.x;
    int rowbase = blockIdx.y * 64;
    int colbase = blockIdx.x * 64;
    float acc[4][4] = {};

    for (int kt = 0; kt < K; kt += BK) {
        {
            int r = tid >> 3;
            int c4 = (tid & 7) * 4;
#pragma unroll
            for (int h = 0; h < 2; ++h) {
                int row = rowbase + r + h * 32;
                int arow = min(row, M - 1);
                float4 v = *(const float4*)(A + (size_t)arow * K + kt + c4);
                As[c4 + 0][r + h * 32] = v.x;
                As[c4 + 1][r + h * 32] = v.y;
                As[c4 + 2][r + h * 32] = v.z;
                As[c4 + 3][r + h * 32] = v.w;
            }
        }
        {
            int kr = tid >> 4;
            int c4 = (tid & 15) * 4;
#pragma unroll
            for (int h = 0; h < 2; ++h) {
                int k = kt + kr + h * 16;
                int col = colbase + c4;
                float4 v;
                if (col + 4 <= N) {
                    v = *(const float4*)(B + (size_t)k * N + col);
                } else {
                    v.x = (col + 0 < N) ? B[(size_t)k * N + col + 0] : 0.f;
                    v.y = (col + 1 < N) ? B[(size_t)k * N + col + 1] : 0.f;
                    v.z = (col + 2 < N) ? B[(size_t)k * N + col + 2] : 0.f;
                    v.w = (col + 3 < N) ? B[(size_t)k * N + col + 3] : 0.f;
                }
                *(float4*)&Bs[kr + h * 16][c4] = v;
            }
        }
        __syncthreads();
        int tm = (tid & 15) * 4;
        int tn = (tid >> 4) * 4;
#pragma unroll
        for (int kk = 0; kk < BK; ++kk) {
            float4 av = *(const float4*)&As[kk][tm];
            float4 bv = *(const float4*)&Bs[kk][tn];
            float a[4] = {av.x, av.y, av.z, av.w};
            float b[4] = {bv.x, bv.y, bv.z, bv.w};
#pragma unroll
            for (int i = 0; i < 4; ++i)
#pragma unroll
                for (int j = 0; j < 4; ++j) acc[i][j] += a[i] * b[j];
        }
        __syncthreads();
    }

    int tm = (tid & 15) * 4;
    int tn = (tid >> 4) * 4;
#pragma unroll
    for (int i = 0; i < 4; ++i) {
        int row = rowbase + tm + i;
        if (row >= M) continue;
#pragma unroll
        for (int j = 0; j < 4; ++j) {
            int col = colbase + tn + j;
            if (col >= N) continue;
            float v = acc[i][j] + bias[col];
            if (RELU) v = fmaxf(v, 0.f);
            C[(size_t)row * N + col] = v;
        }
    }
}

// ---------------- pairwise L2 on [N,3] ----------------
__global__ __launch_bounds__(256) void dist_kernel(const float* __restrict__ y,
                                                   float* __restrict__ out) {
    __shared__ float sa[192];
    __shared__ float sb[192];
    int rb = blockIdx.y * 64;
    int cb = blockIdx.x * 64;
    int tid = threadIdx.x;
    if (tid < 192) {
        int ga = rb * 3 + tid;
        sa[tid] = (ga < 3 * N_NODES) ? y[ga] : 0.f;
        int gb = cb * 3 + tid;
        sb[tid] = (gb < 3 * N_NODES) ? y[gb] : 0.f;
    }
    __syncthreads();
    int ty = tid >> 4;
    int tx = tid & 15;
    int c0 = tx * 4;
#pragma unroll
    for (int i = 0; i < 4; ++i) {
        int r = ty * 4 + i;
        int row = rb + r;
        if (row >= N_NODES) continue;
        float ax = sa[r * 3 + 0], ay = sa[r * 3 + 1], az = sa[r * 3 + 2];
        float res[4];
#pragma unroll
        for (int j = 0; j < 4; ++j) {
            int cc = c0 + j;
            float dx = ax - sb[cc * 3 + 0];
            float dy = ay - sb[cc * 3 + 1];
            float dz = az - sb[cc * 3 + 2];
            res[j] = sqrtf(dx * dx + dy * dy + dz * dz);
        }
        int col = cb + c0;
        size_t base = (size_t)row * N_NODES + col;
        if (col + 4 <= N_NODES) {
            *(float4*)(out + base) = make_float4(res[0], res[1], res[2], res[3]);
        } else {
#pragma unroll
            for (int j = 0; j < 4; ++j)
                if (col + j < N_NODES) out[base + j] = res[j];
        }
    }
}

extern "C" void kernel_launch(void* const* d_in, const int* in_sizes, int n_in,
                              void* d_out, int out_size, void* d_ws, size_t ws_size,
                              hipStream_t stream) {
    const float* x   = (const float*)d_in[0];
    const int*   ei  = (const int*)d_in[1];
    const float* W_l = (const float*)d_in[2];
    const float* b_l = (const float*)d_in[3];
    const float* W_r = (const float*)d_in[4];
    const float* Wa  = (const float*)d_in[5];
    const float* ba  = (const float*)d_in[6];
    const float* W1  = (const float*)d_in[7];
    const float* b1  = (const float*)d_in[8];
    const float* W2  = (const float*)d_in[9];
    const float* b2  = (const float*)d_in[10];
    const float* W3  = (const float*)d_in[11];
    const float* b3  = (const float*)d_in[12];

    float* out = (float*)d_out;
    // big intermediates live in d_out (fully overwritten by dist_kernel at the end)
    float* z    = out;                 // 10000*512 = 5,120,000 f   (x@[W_l|W_r])
    float* h1   = out + 5120000;       // 10000*256 = 2,560,000 f
    float* h2   = out + 7680000;       // 10000*128 = 1,280,000 f
    float* h3   = out + 8960000;       // 10000*64  =   640,000 f
    float* h4   = out + 9600000;       // 10000*32  =   320,000 f

    // small stuff in d_ws (~880 KB)
    float* y        = (float*)d_ws;            // 30,000 f
    int* deg        = (int*)d_ws + 30000;      // 10,000
    int* row_start  = (int*)d_ws + 40000;      // 10,001
    int* cursor     = (int*)d_ws + 50016;      // 10,000
    int* chunk_tot  = (int*)d_ws + 60016;      // 40
    int* csr_src    = (int*)d_ws + 60064;      // 160,000

    hipMemsetAsync(deg, 0, N_NODES * sizeof(int), stream);
    hipMemsetAsync(cursor, 0, N_NODES * sizeof(int), stream);

    // z = x @ [W_l | W_r] : independent of CSR; issue first
    zgemm_kernel<<<dim3(8, 157), 256, 0, stream>>>(x, W_l, W_r, z);

    count_kernel<<<(N_EDGES + 255) / 256, 256, 0, stream>>>(ei, deg);
    scanA_kernel<<<40, 256, 0, stream>>>(deg, row_start, chunk_tot);
    scanC_kernel<<<40, 256, 0, stream>>>(row_start, chunk_tot);
    scatter_kernel<<<(N_EDGES + 255) / 256, 256, 0, stream>>>(ei, row_start, cursor, csr_src);

    // h1 = relu(mean(z_l[src]) + z_r[dst] + b_l)
    aggr_fused_kernel<<<2500, 256, 0, stream>>>(z, csr_src, row_start, b_l, h1);

    dim3 b256(256);
    // h2 = relu(h1@Wa + ba)               [10000,128]
    gemm_kernel<true><<<dim3(2, 157), b256, 0, stream>>>(h1, Wa, ba, h2, N_NODES, 256, 128);
    // h3 = relu(h2@W1 + b1)               [10000,64]
    gemm_kernel<true><<<dim3(1, 157), b256, 0, stream>>>(h2, W1, b1, h3, N_NODES, 128, 64);
    // h4 = relu(h3@W2 + b2)               [10000,32]
    gemm_kernel<true><<<dim3(1, 157), b256, 0, stream>>>(h3, W2, b2, h4, N_NODES, 64, 32);
    // y  = h4@W3 + b3                     [10000,3]
    gemm_kernel<false><<<dim3(1, 157), b256, 0, stream>>>(h4, W3, b3, y, N_NODES, 32, 3);

    dist_kernel<<<dim3(157, 157), b256, 0, stream>>>(y, out);
}

// Round 4
// 634.118 us; speedup vs baseline: 1.6539x; 1.0218x over previous
//
#include <hip/hip_runtime.h>

#define N_NODES 10000
#define N_EDGES 160000

// ---------------- CSR build ----------------
__global__ void count_kernel(const int* __restrict__ ei, int* __restrict__ deg) {
    int e = blockIdx.x * blockDim.x + threadIdx.x;
    if (e < N_EDGES) {
        int dst = ei[N_EDGES + e];
        atomicAdd(&deg[dst], 1);
    }
}

__global__ void scanA_kernel(const int* __restrict__ deg, int* __restrict__ row_start,
                             int* __restrict__ chunk_tot) {
    __shared__ int s[256];
    int c = blockIdx.x, tid = threadIdx.x;
    int i = c * 256 + tid;
    int v = (i < N_NODES) ? deg[i] : 0;
    s[tid] = v;
    __syncthreads();
    for (int off = 1; off < 256; off <<= 1) {
        int t = (tid >= off) ? s[tid - off] : 0;
        __syncthreads();
        s[tid] += t;
        __syncthreads();
    }
    if (i < N_NODES) row_start[i + 1] = s[tid];
    if (tid == 255) chunk_tot[c] = s[255];
}

__global__ void scanC_kernel(int* __restrict__ row_start, const int* __restrict__ chunk_tot) {
    int c = blockIdx.x, tid = threadIdx.x;
    int off = 0;
    for (int cc = 0; cc < c; ++cc) off += chunk_tot[cc];
    int i = c * 256 + tid;
    if (i < N_NODES) row_start[i + 1] += off;
    if (c == 0 && tid == 0) row_start[0] = 0;
}

__global__ void scatter_kernel(const int* __restrict__ ei, const int* __restrict__ row_start,
                               int* __restrict__ cursor, int* __restrict__ csr_src) {
    int e = blockIdx.x * blockDim.x + threadIdx.x;
    if (e < N_EDGES) {
        int src = ei[e];
        int dst = ei[N_EDGES + e];
        int p = atomicAdd(&cursor[dst], 1);
        csr_src[row_start[dst] + p] = src;
    }
}

// ---------------- z = x @ [W_l | W_r]  ([10000,512] @ [512,(256|256)] -> [10000,512]) ----------------
// 128x64 tile, 8x4 microtile (acc=32 regs, no spill), 1.5 B LDS per FMA.
__global__ __launch_bounds__(256) void zgemm_kernel(const float* __restrict__ x,
                                                    const float* __restrict__ W_l,
                                                    const float* __restrict__ W_r,
                                                    float* __restrict__ Z) {
    const int BK = 32;
    __shared__ float As[32][132];  // [k][m], m<128, padded
    __shared__ float Bs[32][68];   // [k][n], n<64
    int tid = threadIdx.x;
    int rowbase = blockIdx.y * 128;
    int colbase = blockIdx.x * 64;               // 0..448
    const float* B = (colbase < 256) ? W_l : W_r;
    int bcol = colbase & 255;                    // col offset within the 256-wide weight
    float acc[8][4] = {};

    // microtile map: tm groups of 8 rows (broadcast-friendly), tn lanes of 4 cols
    int tm = (tid >> 4) * 8;   // 0..120
    int tn = (tid & 15) * 4;   // 0..60

    for (int kt = 0; kt < 512; kt += BK) {
        // A tile 128x32 -> LDS transposed
        {
            int r = tid >> 3;            // 0..31
            int c4 = (tid & 7) * 4;      // 0..28
#pragma unroll
            for (int h = 0; h < 4; ++h) {
                int row = rowbase + r + h * 32;
                int arow = min(row, N_NODES - 1);
                float4 v = *(const float4*)(x + (size_t)arow * 512 + kt + c4);
                As[c4 + 0][r + h * 32] = v.x;
                As[c4 + 1][r + h * 32] = v.y;
                As[c4 + 2][r + h * 32] = v.z;
                As[c4 + 3][r + h * 32] = v.w;
            }
        }
        // B tile 32x64
        {
            int kr = tid >> 4;           // 0..15
            int c4 = (tid & 15) * 4;     // 0..60
#pragma unroll
            for (int h = 0; h < 2; ++h) {
                int k = kt + kr + h * 16;
                float4 v = *(const float4*)(B + (size_t)k * 256 + bcol + c4);
                *(float4*)&Bs[kr + h * 16][c4] = v;
            }
        }
        __syncthreads();
#pragma unroll
        for (int kk = 0; kk < BK; ++kk) {
            float4 av0 = *(const float4*)&As[kk][tm];
            float4 av1 = *(const float4*)&As[kk][tm + 4];
            float4 bv = *(const float4*)&Bs[kk][tn];
            float a[8] = {av0.x, av0.y, av0.z, av0.w, av1.x, av1.y, av1.z, av1.w};
            float b[4] = {bv.x, bv.y, bv.z, bv.w};
#pragma unroll
            for (int i = 0; i < 8; ++i)
#pragma unroll
                for (int j = 0; j < 4; ++j) acc[i][j] += a[i] * b[j];
        }
        __syncthreads();
    }

#pragma unroll
    for (int i = 0; i < 8; ++i) {
        int row = rowbase + tm + i;
        if (row >= N_NODES) continue;
        float* zr = Z + (size_t)row * 512 + colbase + tn;
        *(float4*)(zr) = make_float4(acc[i][0], acc[i][1], acc[i][2], acc[i][3]);
    }
}

// ---------------- fused mean-aggregation + SAGE epilogue ----------------
// h1[dst] = relu( mean_{src->dst} z[src, 0:256] + z[dst, 256:512] + b_l )
__global__ __launch_bounds__(256) void aggr_fused_kernel(const float* __restrict__ z,
                                                         const int* __restrict__ csr_src,
                                                         const int* __restrict__ row_start,
                                                         const float* __restrict__ b_l,
                                                         float* __restrict__ h1) {
    int lane = threadIdx.x & 63;
    int dst = blockIdx.x * 4 + (threadIdx.x >> 6);
    int beg = row_start[dst], end = row_start[dst + 1];
    float4 acc = make_float4(0.f, 0.f, 0.f, 0.f);
    int i = beg;
    for (; i + 1 < end; i += 2) {
        int s0 = csr_src[i];
        int s1 = csr_src[i + 1];
        float4 v0 = *((const float4*)(z + (size_t)s0 * 512) + lane);
        float4 v1 = *((const float4*)(z + (size_t)s1 * 512) + lane);
        acc.x += v0.x + v1.x; acc.y += v0.y + v1.y;
        acc.z += v0.z + v1.z; acc.w += v0.w + v1.w;
    }
    if (i < end) {
        int s0 = csr_src[i];
        float4 v0 = *((const float4*)(z + (size_t)s0 * 512) + lane);
        acc.x += v0.x; acc.y += v0.y; acc.z += v0.z; acc.w += v0.w;
    }
    float inv = 1.0f / (float)max(end - beg, 1);
    float4 r = *((const float4*)(z + (size_t)dst * 512 + 256) + lane);
    float4 bb = *((const float4*)b_l + lane);
    float4 o;
    o.x = fmaxf(fmaf(acc.x, inv, r.x + bb.x), 0.f);
    o.y = fmaxf(fmaf(acc.y, inv, r.y + bb.y), 0.f);
    o.z = fmaxf(fmaf(acc.z, inv, r.z + bb.z), 0.f);
    o.w = fmaxf(fmaf(acc.w, inv, r.w + bb.w), 0.f);
    *((float4*)(h1 + (size_t)dst * 256) + lane) = o;
}

// ---------------- fused tail: h1 -> h2 -> h3 -> h4 -> y, all in LDS per 64-row block ----------------
__global__ __launch_bounds__(256) void tail_kernel(const float* __restrict__ h1,
                                                   const float* __restrict__ Wa, const float* __restrict__ ba,
                                                   const float* __restrict__ W1, const float* __restrict__ b1,
                                                   const float* __restrict__ W2, const float* __restrict__ b2,
                                                   const float* __restrict__ W3, const float* __restrict__ b3,
                                                   float* __restrict__ y) {
    __shared__ float As[32][68];    // A staging [k][m]
    __shared__ float SB[32][132];   // B staging [k][n] (also reused flat for W2)
    __shared__ float H2T[128][68];  // h2 tile transposed [col][row]
    __shared__ float H3T[64][68];   // h3 tile transposed
    __shared__ float H4T[32][68];   // h4 tile transposed
    int tid = threadIdx.x;
    int rowbase = blockIdx.x * 64;

    int tm = (tid & 15) * 4;   // 0..60  (64 rows)

    // ---- stage 1: h2 = relu(h1_tile @ Wa + ba), K=256, N=128 ----
    {
        int tn = (tid >> 4) * 8;   // 0..120 (128 cols)
        float acc[4][8] = {};
        for (int kt = 0; kt < 256; kt += 32) {
            // A tile 64x32 transposed
            {
                int r = tid >> 3;           // 0..31
                int c4 = (tid & 7) * 4;     // 0..28
#pragma unroll
                for (int h = 0; h < 2; ++h) {
                    int row = rowbase + r + h * 32;
                    int arow = min(row, N_NODES - 1);
                    float4 v = *(const float4*)(h1 + (size_t)arow * 256 + kt + c4);
                    As[c4 + 0][r + h * 32] = v.x;
                    As[c4 + 1][r + h * 32] = v.y;
                    As[c4 + 2][r + h * 32] = v.z;
                    As[c4 + 3][r + h * 32] = v.w;
                }
            }
            // B tile 32x128
            {
                int kr = tid >> 3;          // 0..31
                int cc = (tid & 7) * 16;    // 0..112
                const float* bp = Wa + (size_t)(kt + kr) * 128 + cc;
                *(float4*)&SB[kr][cc + 0]  = *(const float4*)(bp + 0);
                *(float4*)&SB[kr][cc + 4]  = *(const float4*)(bp + 4);
                *(float4*)&SB[kr][cc + 8]  = *(const float4*)(bp + 8);
                *(float4*)&SB[kr][cc + 12] = *(const float4*)(bp + 12);
            }
            __syncthreads();
#pragma unroll
            for (int kk = 0; kk < 32; ++kk) {
                float4 av = *(const float4*)&As[kk][tm];
                float4 bv0 = *(const float4*)&SB[kk][tn];
                float4 bv1 = *(const float4*)&SB[kk][tn + 4];
                float a[4] = {av.x, av.y, av.z, av.w};
                float b[8] = {bv0.x, bv0.y, bv0.z, bv0.w, bv1.x, bv1.y, bv1.z, bv1.w};
#pragma unroll
                for (int i = 0; i < 4; ++i)
#pragma unroll
                    for (int j = 0; j < 8; ++j) acc[i][j] += a[i] * b[j];
            }
            __syncthreads();
        }
        // bias + relu, store transposed
#pragma unroll
        for (int j = 0; j < 8; ++j) {
            float bj = ba[tn + j];
#pragma unroll
            for (int i = 0; i < 4; ++i)
                H2T[tn + j][tm + i] = fmaxf(acc[i][j] + bj, 0.f);
        }
        __syncthreads();
    }

    // ---- stage 2: h3 = relu(h2 @ W1 + b1), K=128, N=64 ----
    {
        int tn = (tid >> 4) * 4;   // 0..60 (64 cols)
        float acc[4][4] = {};
        for (int kt = 0; kt < 128; kt += 32) {
            {
                int kr = tid >> 3;          // 0..31
                int cc = (tid & 7) * 8;     // 0..56
                const float* bp = W1 + (size_t)(kt + kr) * 64 + cc;
                *(float4*)&SB[kr][cc + 0] = *(const float4*)(bp + 0);
                *(float4*)&SB[kr][cc + 4] = *(const float4*)(bp + 4);
            }
            __syncthreads();
#pragma unroll
            for (int kk = 0; kk < 32; ++kk) {
                float4 av = *(const float4*)&H2T[kt + kk][tm];
                float4 bv = *(const float4*)&SB[kk][tn];
                float a[4] = {av.x, av.y, av.z, av.w};
                float b[4] = {bv.x, bv.y, bv.z, bv.w};
#pragma unroll
                for (int i = 0; i < 4; ++i)
#pragma unroll
                    for (int j = 0; j < 4; ++j) acc[i][j] += a[i] * b[j];
            }
            __syncthreads();
        }
#pragma unroll
        for (int j = 0; j < 4; ++j) {
            float bj = b1[tn + j];
#pragma unroll
            for (int i = 0; i < 4; ++i)
                H3T[tn + j][tm + i] = fmaxf(acc[i][j] + bj, 0.f);
        }
        // no sync needed yet: next writes go to SB, protected by the loop's last sync
    }

    // ---- stage 3: h4 = relu(h3 @ W2 + b2), K=64, N=32 ----
    {
        float* SBf = &SB[0][0];  // flat capacity 32*132 = 4224 >= 64*36
        {
            int r = tid >> 2;        // 0..63
            int c = (tid & 3) * 8;   // 0,8,16,24
            const float* bp = W2 + (size_t)r * 32 + c;
            *(float4*)&SBf[r * 36 + c + 0] = *(const float4*)(bp + 0);
            *(float4*)&SBf[r * 36 + c + 4] = *(const float4*)(bp + 4);
        }
        __syncthreads();   // H3T + W2 staging visible
        int tn = (tid >> 4) * 2;   // 0..30 (32 cols)
        float acc[4][2] = {};
#pragma unroll
        for (int kk = 0; kk < 64; ++kk) {
            float4 av = *(const float4*)&H3T[kk][tm];
            float b0 = SBf[kk * 36 + tn + 0];
            float b1v = SBf[kk * 36 + tn + 1];
            float a[4] = {av.x, av.y, av.z, av.w};
#pragma unroll
            for (int i = 0; i < 4; ++i) {
                acc[i][0] += a[i] * b0;
                acc[i][1] += a[i] * b1v;
            }
        }
#pragma unroll
        for (int j = 0; j < 2; ++j) {
            float bj = b2[tn + j];
#pragma unroll
            for (int i = 0; i < 4; ++i)
                H4T[tn + j][tm + i] = fmaxf(acc[i][j] + bj, 0.f);
        }
        __syncthreads();
    }

    // ---- stage 4: y = h4 @ W3 + b3, K=32, N=3 ----
    {
        int row = tid >> 2;        // 0..63
        int col = tid & 3;         // 0..3
        if (col < 3) {
            float s = b3[col];
#pragma unroll
            for (int k = 0; k < 32; ++k)
                s += H4T[k][row] * W3[k * 3 + col];
            int grow = rowbase + row;
            if (grow < N_NODES) y[(size_t)grow * 3 + col] = s;
        }
    }
}

// ---------------- pairwise L2 on [N,3] ----------------
__global__ __launch_bounds__(256) void dist_kernel(const float* __restrict__ y,
                                                   float* __restrict__ out) {
    __shared__ float sa[192];
    __shared__ float sb[192];
    int rb = blockIdx.y * 64;
    int cb = blockIdx.x * 64;
    int tid = threadIdx.x;
    if (tid < 192) {
        int ga = rb * 3 + tid;
        sa[tid] = (ga < 3 * N_NODES) ? y[ga] : 0.f;
        int gb = cb * 3 + tid;
        sb[tid] = (gb < 3 * N_NODES) ? y[gb] : 0.f;
    }
    __syncthreads();
    int ty = tid >> 4;
    int tx = tid & 15;
    int c0 = tx * 4;
#pragma unroll
    for (int i = 0; i < 4; ++i) {
        int r = ty * 4 + i;
        int row = rb + r;
        if (row >= N_NODES) continue;
        float ax = sa[r * 3 + 0], ay = sa[r * 3 + 1], az = sa[r * 3 + 2];
        float res[4];
#pragma unroll
        for (int j = 0; j < 4; ++j) {
            int cc = c0 + j;
            float dx = ax - sb[cc * 3 + 0];
            float dy = ay - sb[cc * 3 + 1];
            float dz = az - sb[cc * 3 + 2];
            res[j] = sqrtf(dx * dx + dy * dy + dz * dz);
        }
        int col = cb + c0;
        size_t base = (size_t)row * N_NODES + col;
        if (col + 4 <= N_NODES) {
            *(float4*)(out + base) = make_float4(res[0], res[1], res[2], res[3]);
        } else {
#pragma unroll
            for (int j = 0; j < 4; ++j)
                if (col + j < N_NODES) out[base + j] = res[j];
        }
    }
}

extern "C" void kernel_launch(void* const* d_in, const int* in_sizes, int n_in,
                              void* d_out, int out_size, void* d_ws, size_t ws_size,
                              hipStream_t stream) {
    const float* x   = (const float*)d_in[0];
    const int*   ei  = (const int*)d_in[1];
    const float* W_l = (const float*)d_in[2];
    const float* b_l = (const float*)d_in[3];
    const float* W_r = (const float*)d_in[4];
    const float* Wa  = (const float*)d_in[5];
    const float* ba  = (const float*)d_in[6];
    const float* W1  = (const float*)d_in[7];
    const float* b1  = (const float*)d_in[8];
    const float* W2  = (const float*)d_in[9];
    const float* b2  = (const float*)d_in[10];
    const float* W3  = (const float*)d_in[11];
    const float* b3  = (const float*)d_in[12];

    float* out = (float*)d_out;
    // big intermediates live in d_out (fully overwritten by dist_kernel at the end)
    float* z    = out;                 // 10000*512 = 5,120,000 f   (x@[W_l|W_r])
    float* h1   = out + 5120000;       // 10000*256 = 2,560,000 f

    // small stuff in d_ws (~880 KB)
    float* y        = (float*)d_ws;            // 30,000 f
    int* deg        = (int*)d_ws + 30000;      // 10,000
    int* row_start  = (int*)d_ws + 40000;      // 10,001
    int* cursor     = (int*)d_ws + 50016;      // 10,000
    int* chunk_tot  = (int*)d_ws + 60016;      // 40
    int* csr_src    = (int*)d_ws + 60064;      // 160,000

    hipMemsetAsync(deg, 0, N_NODES * sizeof(int), stream);
    hipMemsetAsync(cursor, 0, N_NODES * sizeof(int), stream);

    // z = x @ [W_l | W_r] : independent of CSR; issue first
    zgemm_kernel<<<dim3(8, 79), 256, 0, stream>>>(x, W_l, W_r, z);

    count_kernel<<<(N_EDGES + 255) / 256, 256, 0, stream>>>(ei, deg);
    scanA_kernel<<<40, 256, 0, stream>>>(deg, row_start, chunk_tot);
    scanC_kernel<<<40, 256, 0, stream>>>(row_start, chunk_tot);
    scatter_kernel<<<(N_EDGES + 255) / 256, 256, 0, stream>>>(ei, row_start, cursor, csr_src);

    // h1 = relu(mean(z_l[src]) + z_r[dst] + b_l)
    aggr_fused_kernel<<<2500, 256, 0, stream>>>(z, csr_src, row_start, b_l, h1);

    // h2..y fused, 64 rows per block
    tail_kernel<<<157, 256, 0, stream>>>(h1, Wa, ba, W1, b1, W2, b2, W3, b3, y);

    dist_kernel<<<dim3(157, 157), 256, 0, stream>>>(y, out);
}